// Round 8
// baseline (512.286 us; speedup 1.0000x reference)
//
#include <hip/hip_runtime.h>

// Problem constants: B=2 H=32 L=4096 D=128 T=2048 G=4
// Output layout (flat f32): k_cache[33554432] | v_cache[33554432] | pos[262144]
//
// Single fused kernel, one launch:
//   blocks 0..2047   : kv — each block owns a contiguous 4096-f4 chunk, fully
//                      inside one (b,h) -> fill_indices[h] hoisted to scalar.
//   blocks 2048..2111: pos — each block owns one (b,h) row of 4096 entries.

typedef float f4 __attribute__((ext_vector_type(4)));

__global__ __launch_bounds__(256) void kv_fused(
    const f4* __restrict__ k_cache, const f4* __restrict__ v_cache,
    const f4* __restrict__ k_val,   const f4* __restrict__ v_val,
    const int* __restrict__ fill_indices,
    const f4* __restrict__ k_step,  const f4* __restrict__ v_step,
    const int* __restrict__ pos_in, const int* __restrict__ input_pos,
    const int* __restrict__ input_pos_step,
    f4* __restrict__ outK, f4* __restrict__ outV, float* __restrict__ outPos)
{
    const int b = blockIdx.x;
    if (b < 2048) {
        const int base = b << 12;          // first f4 index of this chunk
        const int bh   = base >> 17;       // uniform per block (32 blocks/bh)
        const int fi   = fill_indices[bh & 31];   // scalar load, once
        const int sstep = bh << 5;         // k_step/v_step f4 base for this bh
#pragma unroll
        for (int it = 0; it < 16; ++it) {
            const int i  = base + (it << 8) + (int)threadIdx.x;
            const int w  = i & 131071;     // l*32 + d4 within this bh
            const int l  = w >> 5;
            f4 kv, vv;
            if (l == fi) {                 // decode-step slot (rare, cached)
                const int s = sstep + (i & 31);
                kv = k_step[s];
                vv = v_step[s];
            } else if (w < 65536) {        // l < T: prefill from val
                const int s = (bh << 16) + w;
                kv = __builtin_nontemporal_load(&k_val[s]);
                vv = __builtin_nontemporal_load(&v_val[s]);
            } else {                       // tail: copy input cache
                kv = __builtin_nontemporal_load(&k_cache[i]);
                vv = __builtin_nontemporal_load(&v_cache[i]);
            }
            __builtin_nontemporal_store(kv, &outK[i]);
            __builtin_nontemporal_store(vv, &outV[i]);
        }
    } else {
        // pos: block (b-2048) = one bh row, 4096 entries.
        const int bh    = b - 2048;
        const int pbase = bh << 12;
        const int fi    = fill_indices[bh & 31];
        const int ps    = input_pos_step[0];
#pragma unroll
        for (int it = 0; it < 16; ++it) {
            const int idx = pbase + (it << 8) + (int)threadIdx.x;
            const int l   = idx & 4095;
            int p;
            if (l == fi)        p = ps;
            else if (l < 4)     p = 4096;          // mark_global_tokens = L
            else if (l < 2048)  p = input_pos[l];
            else                p = pos_in[idx];
            outPos[idx] = (float)p;                // harness reads f32
        }
    }
}

extern "C" void kernel_launch(void* const* d_in, const int* in_sizes, int n_in,
                              void* d_out, int out_size, void* d_ws, size_t ws_size,
                              hipStream_t stream) {
    const float* k_cache = (const float*)d_in[0];
    const float* v_cache = (const float*)d_in[1];
    const int*   pos_in  = (const int*)d_in[2];
    const int*   input_pos = (const int*)d_in[3];
    const float* k_val   = (const float*)d_in[4];
    const float* v_val   = (const float*)d_in[5];
    const int*   fill_indices = (const int*)d_in[6];
    const float* k_step  = (const float*)d_in[7];
    const float* v_step  = (const float*)d_in[8];
    const int*   input_pos_step = (const int*)d_in[9];

    const long KC = 33554432;              // floats per cache
    float* outK = (float*)d_out;
    float* outV = outK + KC;
    float* outPos = outV + KC;

    kv_fused<<<2048 + 64, 256, 0, stream>>>(
        (const f4*)k_cache, (const f4*)v_cache,
        (const f4*)k_val,   (const f4*)v_val,
        fill_indices,
        (const f4*)k_step,  (const f4*)v_step,
        pos_in, input_pos, input_pos_step,
        (f4*)outK, (f4*)outV, outPos);
}

// Round 13
// 495.340 us; speedup vs baseline: 1.0342x; 1.0342x over previous
//
#include <hip/hip_runtime.h>

// Problem constants: B=2 H=32 L=4096 D=128 T=2048 G=4
// Output layout (flat f32): k_cache[33554432] | v_cache[33554432] | pos[262144]
//
// R6 structure (best: 489 us): hot kernel = branchless streaming copy with
// machine-wide grid-stride sweep; fixup kernel = 64 fill-slot overrides + pos.
// R9 delta: source selected via pointer cndmask instead of if/else branch.

typedef float f4 __attribute__((ext_vector_type(4)));

// i indexes output f4s: bh = i>>17 (64 values), w = i&131071 = l*32+d4.
// w < 65536  <=>  l < 2048  -> source k_val/v_val (contiguous per bh)
// else                      -> source k_cache/v_cache (same index as out)
__global__ __launch_bounds__(256) void kv_copy(
    const f4* __restrict__ k_cache, const f4* __restrict__ v_cache,
    const f4* __restrict__ k_val,   const f4* __restrict__ v_val,
    f4* __restrict__ outK, f4* __restrict__ outV)
{
    const int total  = 8388608;                 // 2*32*4096*32 f4
    const int stride = gridDim.x * blockDim.x;  // 524288 -> exactly 16 iters
    int i = blockIdx.x * blockDim.x + threadIdx.x;
#pragma unroll 4
    for (; i < total; i += stride) {
        const int w = i & 131071;
        const int s = ((i >> 17) << 16) + (w & 65535);   // val-side index
        const bool pre = (w < 65536);
        const f4* kp = pre ? &k_val[s] : &k_cache[i];    // pointer select,
        const f4* vp = pre ? &v_val[s] : &v_cache[i];    // single load site
        f4 kv = __builtin_nontemporal_load(kp);
        f4 vv = __builtin_nontemporal_load(vp);
        __builtin_nontemporal_store(kv, &outK[i]);
        __builtin_nontemporal_store(vv, &outV[i]);
    }
}

// Runs after kv_copy (stream-ordered): per-head fill-slot step writes + pos.
// pos priority: step > global-mark(4096) > input_pos[l] > original pos.
// Output read back as float32 -> write float-encoded ints.
__global__ __launch_bounds__(256) void fixup(
    const int* __restrict__ pos_in,
    const int* __restrict__ input_pos,
    const int* __restrict__ fill_indices,
    const int* __restrict__ input_pos_step,
    const f4* __restrict__ k_step, const f4* __restrict__ v_step,
    f4* __restrict__ outK, f4* __restrict__ outV, float* __restrict__ outPos)
{
    const int i = blockIdx.x * blockDim.x + threadIdx.x;
    if (i < 262144) {                           // pos: B*H*L
        const int l = i & 4095;
        const int h = (i >> 12) & 31;
        const int fi = fill_indices[h];
        int p;
        if (l == fi)        p = input_pos_step[0];
        else if (l < 4)     p = 4096;           // mark_global_tokens: = L
        else if (l < 2048)  p = input_pos[l];
        else                p = pos_in[i];
        outPos[i] = (float)p;
    } else if (i < 262144 + 2048) {             // step scatter: 64 bh * 32 d4
        const int j  = i - 262144;
        const int bh = j >> 5;
        const int d4 = j & 31;
        const int fi = fill_indices[bh & 31];
        const int s  = (bh << 5) + d4;          // k_step[b,h,0,d]
        const int o  = (bh << 17) + (fi << 5) + d4;
        outK[o] = k_step[s];
        outV[o] = v_step[s];
    }
}

extern "C" void kernel_launch(void* const* d_in, const int* in_sizes, int n_in,
                              void* d_out, int out_size, void* d_ws, size_t ws_size,
                              hipStream_t stream) {
    const float* k_cache = (const float*)d_in[0];
    const float* v_cache = (const float*)d_in[1];
    const int*   pos_in  = (const int*)d_in[2];
    const int*   input_pos = (const int*)d_in[3];
    const float* k_val   = (const float*)d_in[4];
    const float* v_val   = (const float*)d_in[5];
    const int*   fill_indices = (const int*)d_in[6];
    const float* k_step  = (const float*)d_in[7];
    const float* v_step  = (const float*)d_in[8];
    const int*   input_pos_step = (const int*)d_in[9];

    const long KC = 33554432;                   // floats per cache
    float* outK = (float*)d_out;
    float* outV = outK + KC;
    float* outPos = outV + KC;

    // 2048 blocks * 256 thr = full occupancy, 16 f4/thread, machine-wide
    // contiguous sweep (beats per-block chunks: R8 +23us regression).
    kv_copy<<<2048, 256, 0, stream>>>(
        (const f4*)k_cache, (const f4*)v_cache,
        (const f4*)k_val,   (const f4*)v_val,
        (f4*)outK, (f4*)outV);

    fixup<<<(262144 + 2048 + 255) / 256, 256, 0, stream>>>(
        pos_in, input_pos, fill_indices, input_pos_step,
        (const f4*)k_step, (const f4*)v_step,
        (f4*)outK, (f4*)outV, outPos);
}